// Round 5
// baseline (331.083 us; speedup 1.0000x reference)
//
#include <hip/hip_runtime.h>
#include <hip/hip_bf16.h>
#include <hip/hip_cooperative_groups.h>

namespace cg = cooperative_groups;

#define Sx 256
#define Dx 300
#define Mx 1024
#define CC 5.0f

// workspace layout (float offsets)
#define OFF_REP    0
#define OFF_DEP    307200
#define OFF_HEAD   614400
#define OFF_ATTN   921600
#define OFF_WTFC   1228800   // [300k][300g]
#define OFF_WT12   1318800   // [300k][600g]  g<300: W1 (dep), g>=300: W2 (head)
#define OFF_WTF12  1498800   // [600k][300g]  k<300: Wf1, k>=300: Wf2
#define OFF_BIAS   1678800   // bfc@+0, b1@+304, bf@+608

__device__ __forceinline__ float bf2f(unsigned short u) {
    union { unsigned int i; float f; } v;
    v.i = ((unsigned int)u) << 16;
    return v.f;
}

// weights ~N(0,0.05): bf16 interp of true bf16 -> all |v|<1; fp32 halves -> ~2e-10
__device__ __forceinline__ int detect_bf16(const void* w) {
    const unsigned short* u = (const unsigned short*)w;
    int ok = 1;
    #pragma unroll
    for (int t = 0; t < 64; ++t) {
        float v = bf2f(u[t]);
        ok &= (fabsf(v) < 1.0f) ? 1 : 0;
    }
    return ok;
}

__device__ __forceinline__ float ldf(const void* p, int idx, int isbf) {
    return isbf ? bf2f(((const unsigned short*)p)[idx]) : ((const float*)p)[idx];
}

// ---------------------------------------------------------------------------
// Single fused cooperative kernel: grid 256 x 320.
// Phase 0: weight transpose (+biases) -> ws
// Phase 1: rep = elu(X @ Wfc^T + bfc)
// Phase 2: dep = rep@W1^T + b1 ; head = rep@W2^T  (two g-passes)
// Phase 3: branchless single-pass attention (fixed shift m=C)
// Phase 4: gate + blend + mask -> out
// ---------------------------------------------------------------------------
__global__ __launch_bounds__(320) void k_fused(
        const void* __restrict__ Xv, const int* __restrict__ mask,
        const void* __restrict__ Wfc, const void* __restrict__ bfc,
        const void* __restrict__ W1,  const void* __restrict__ W2,
        const void* __restrict__ b1,  const void* __restrict__ Wf1,
        const void* __restrict__ Wf2, const void* __restrict__ bfv,
        float* __restrict__ ws, void* __restrict__ outv) {
    cg::grid_group grid = cg::this_grid();
    __shared__ __align__(16) float Xs[4][608];
    __shared__ float tile[32][33];
    __shared__ float mkf[256];
    __shared__ int s_isbf;

    const int tid = threadIdx.x;
    const int blk = blockIdx.x;

    // ---------------- Phase 0: prep (transpose weights, biases) ----------
    if (tid == 0) s_isbf = detect_bf16(Wfc);
    __syncthreads();
    const int isbf = s_isbf;

    if (blk == 255) {
        for (int idx = tid; idx < 912; idx += 320) {
            int wb = idx / 304, o = idx - wb * 304;
            const void* src = (wb == 0) ? bfc : (wb == 1 ? b1 : bfv);
            ws[OFF_BIAS + idx] = (o < Dx) ? ldf(src, o, isbf) : 0.0f;
        }
    }
    for (int job = 2 * blk; job <= 2 * blk + 1; ++job) {
        if (job >= 500) break;
        const int jm = job / 100, t = job % 100;
        const int tg = t / 10, tk = t % 10;
        const void* src; float* dst; int stride, rowOff, colOff;
        switch (jm) {
            case 0:  src = Wfc; dst = ws + OFF_WTFC;  stride = 300; rowOff = 0;   colOff = 0;   break;
            case 1:  src = W1;  dst = ws + OFF_WT12;  stride = 600; rowOff = 0;   colOff = 0;   break;
            case 2:  src = W2;  dst = ws + OFF_WT12;  stride = 600; rowOff = 0;   colOff = 300; break;
            case 3:  src = Wf1; dst = ws + OFF_WTF12; stride = 300; rowOff = 0;   colOff = 0;   break;
            default: src = Wf2; dst = ws + OFF_WTF12; stride = 300; rowOff = 300; colOff = 0;   break;
        }
        __syncthreads();
        if (tid < 256) {
            const int tx = tid & 31, ty = tid >> 5;
            #pragma unroll
            for (int r = 0; r < 4; ++r) {
                int g = tg * 32 + ty + r * 8, k = tk * 32 + tx;
                if (g < Dx && k < Dx) tile[ty + r * 8][tx] = ldf(src, g * Dx + k, isbf);
            }
        }
        __syncthreads();
        if (tid < 256) {
            const int tx = tid & 31, ty = tid >> 5;
            #pragma unroll
            for (int r = 0; r < 4; ++r) {
                int k = tk * 32 + ty + r * 8, g = tg * 32 + tx;
                if (g < Dx && k < Dx) dst[(k + rowOff) * stride + colOff + g] = tile[tx][ty + r * 8];
            }
        }
    }
    grid.sync();

    // ---------------- Phase 1: rep = elu(X @ Wfc^T + bfc) ----------------
    const int m0 = blk * 4;
    {
        if (isbf) {
            const unsigned short* X = (const unsigned short*)Xv;
            for (int idx = tid; idx < 4 * Dx; idx += 320) {
                int r = idx / Dx, c = idx - r * Dx;
                Xs[r][c] = bf2f(X[m0 * Dx + idx]);
            }
        } else {
            const float* X = (const float*)Xv;
            for (int idx = tid; idx < 4 * Dx; idx += 320) {
                int r = idx / Dx, c = idx - r * Dx;
                Xs[r][c] = X[m0 * Dx + idx];
            }
        }
        __syncthreads();
        const int g = tid;
        if (g < Dx) {
            float a0 = 0.f, a1 = 0.f, a2 = 0.f, a3 = 0.f;
            const float* wp = ws + OFF_WTFC + g;
            #pragma unroll 4
            for (int k = 0; k < Dx; k += 4) {
                float w0 = wp[(k + 0) * 300], w1 = wp[(k + 1) * 300];
                float w2 = wp[(k + 2) * 300], w3 = wp[(k + 3) * 300];
                float4 x0 = *(const float4*)(&Xs[0][k]);
                float4 x1 = *(const float4*)(&Xs[1][k]);
                float4 x2 = *(const float4*)(&Xs[2][k]);
                float4 x3 = *(const float4*)(&Xs[3][k]);
                a0 += x0.x * w0 + x0.y * w1 + x0.z * w2 + x0.w * w3;
                a1 += x1.x * w0 + x1.y * w1 + x1.z * w2 + x1.w * w3;
                a2 += x2.x * w0 + x2.y * w1 + x2.z * w2 + x2.w * w3;
                a3 += x3.x * w0 + x3.y * w1 + x3.z * w2 + x3.w * w3;
            }
            float bb = ws[OFF_BIAS + g];
            float acc[4] = {a0, a1, a2, a3};
            #pragma unroll
            for (int r = 0; r < 4; ++r) {
                float v = acc[r] + bb;
                v = v > 0.f ? v : (__expf(v) - 1.0f);
                ws[OFF_REP + (m0 + r) * Dx + g] = v;
            }
        }
    }
    grid.sync();

    // ---------------- Phase 2: dep/head (two g-passes over staged rep) ---
    {
        for (int idx = tid; idx < 4 * Dx; idx += 320) {
            int r = idx / Dx, c = idx - r * Dx;
            Xs[r][c] = ws[OFF_REP + m0 * Dx + idx];
        }
        __syncthreads();
        #pragma unroll
        for (int pass = 0; pass < 2; ++pass) {
            const int g = tid + pass * 300;
            if (tid < Dx) {
                float a0 = 0.f, a1 = 0.f, a2 = 0.f, a3 = 0.f;
                const float* wp = ws + OFF_WT12 + g;
                #pragma unroll 4
                for (int k = 0; k < Dx; k += 4) {
                    float w0 = wp[(k + 0) * 600], w1 = wp[(k + 1) * 600];
                    float w2 = wp[(k + 2) * 600], w3 = wp[(k + 3) * 600];
                    float4 x0 = *(const float4*)(&Xs[0][k]);
                    float4 x1 = *(const float4*)(&Xs[1][k]);
                    float4 x2 = *(const float4*)(&Xs[2][k]);
                    float4 x3 = *(const float4*)(&Xs[3][k]);
                    a0 += x0.x * w0 + x0.y * w1 + x0.z * w2 + x0.w * w3;
                    a1 += x1.x * w0 + x1.y * w1 + x1.z * w2 + x1.w * w3;
                    a2 += x2.x * w0 + x2.y * w1 + x2.z * w2 + x2.w * w3;
                    a3 += x3.x * w0 + x3.y * w1 + x3.z * w2 + x3.w * w3;
                }
                if (pass == 0) {
                    float bb = ws[OFF_BIAS + 304 + tid];
                    ws[OFF_DEP + (m0 + 0) * Dx + tid] = a0 + bb;
                    ws[OFF_DEP + (m0 + 1) * Dx + tid] = a1 + bb;
                    ws[OFF_DEP + (m0 + 2) * Dx + tid] = a2 + bb;
                    ws[OFF_DEP + (m0 + 3) * Dx + tid] = a3 + bb;
                } else {
                    ws[OFF_HEAD + (m0 + 0) * Dx + tid] = a0;
                    ws[OFF_HEAD + (m0 + 1) * Dx + tid] = a1;
                    ws[OFF_HEAD + (m0 + 2) * Dx + tid] = a2;
                    ws[OFF_HEAD + (m0 + 3) * Dx + tid] = a3;
                }
            }
        }
    }
    grid.sync();

    // ---------------- Phase 3: attention (2 balanced tile-pairs/block) ---
    {
        const float* dep  = ws + OFF_DEP;
        const float* head = ws + OFF_HEAD;
        const float* rep  = ws + OFF_REP;
        const int b = blk >> 6;          // 0..3
        const int q = blk & 63;          // 0..63
        if (tid < 256) mkf[tid] = (float)mask[b * 256 + tid];
        __syncthreads();
        const int d = tid;
        if (d < Dx) {
            const int base = b * 256;
            #pragma unroll
            for (int half = 0; half < 2; ++half) {
                const int i0 = half ? (254 - 2 * q) : (2 * q);
                const float hv0 = head[(base + i0) * Dx + d];
                const float hv1 = head[(base + i0 + 1) * Dx + d];
                const float pw0 = __expf(0.4f * hv0);
                const float pw1 = __expf(0.4f * hv1);
                float s0 = 0.f, r0 = 0.f, s1 = 0.f, r1 = 0.f;
                {   // j = i0+1: attends to i0 only
                    const int j = i0 + 1;
                    float dv = dep[(base + j) * Dx + d];
                    float rv = rep[(base + j) * Dx + d];
                    float mk = mkf[j];
                    float ex = __expf(0.4f * dv);
                    float u0 = fmaf(ex, pw0, 1.0f);
                    float e0 = __expf(-10.0f * __builtin_amdgcn_rcpf(u0));
                    float em0 = e0 * mk;
                    s0 += em0; r0 = fmaf(em0, rv, r0);
                }
                const float* dp = dep + base * Dx + d;
                const float* rp = rep + base * Dx + d;
                #pragma unroll 4
                for (int j = i0 + 2; j < 256; ++j) {
                    float dv = dp[j * Dx];
                    float rv = rp[j * Dx];
                    float mk = mkf[j];
                    float ex = __expf(0.4f * dv);
                    float u0 = fmaf(ex, pw0, 1.0f);
                    float u1 = fmaf(ex, pw1, 1.0f);
                    float e0 = __expf(-10.0f * __builtin_amdgcn_rcpf(u0));
                    float e1 = __expf(-10.0f * __builtin_amdgcn_rcpf(u1));
                    float em0 = e0 * mk;
                    float em1 = e1 * mk;
                    s0 += em0; r0 = fmaf(em0, rv, r0);
                    s1 += em1; r1 = fmaf(em1, rv, r1);
                }
                const float den0 = s0 + (s0 == 0.f ? 1.f : 0.f) + 1e-20f;
                const float den1 = s1 + (s1 == 0.f ? 1.f : 0.f) + 1e-20f;
                ws[OFF_ATTN + (base + i0) * Dx + d]     = r0 / den0;
                ws[OFF_ATTN + (base + i0 + 1) * Dx + d] = r1 / den1;
            }
        }
    }
    grid.sync();

    // ---------------- Phase 4: gate + blend + mask -> out ----------------
    {
        __syncthreads();
        for (int idx = tid; idx < 4 * Dx; idx += 320) {
            int r = idx / Dx, c = idx - r * Dx;
            Xs[r][c]      = ws[OFF_REP + m0 * Dx + idx];
            Xs[r][Dx + c] = ws[OFF_ATTN + m0 * Dx + idx];
        }
        __syncthreads();
        const int g = tid;
        if (g < Dx) {
            float a0 = 0.f, a1 = 0.f, a2 = 0.f, a3 = 0.f;
            const float* wp = ws + OFF_WTF12 + g;
            #pragma unroll 4
            for (int k = 0; k < 600; k += 4) {
                float w0 = wp[(k + 0) * 300], w1 = wp[(k + 1) * 300];
                float w2 = wp[(k + 2) * 300], w3 = wp[(k + 3) * 300];
                float4 x0 = *(const float4*)(&Xs[0][k]);
                float4 x1 = *(const float4*)(&Xs[1][k]);
                float4 x2 = *(const float4*)(&Xs[2][k]);
                float4 x3 = *(const float4*)(&Xs[3][k]);
                a0 += x0.x * w0 + x0.y * w1 + x0.z * w2 + x0.w * w3;
                a1 += x1.x * w0 + x1.y * w1 + x1.z * w2 + x1.w * w3;
                a2 += x2.x * w0 + x2.y * w1 + x2.z * w2 + x2.w * w3;
                a3 += x3.x * w0 + x3.y * w1 + x3.z * w2 + x3.w * w3;
            }
            float bb = ws[OFF_BIAS + 608 + g];
            float acc[4] = {a0, a1, a2, a3};
            #pragma unroll
            for (int r = 0; r < 4; ++r) {
                float gp = acc[r] + bb;
                float gate = 1.0f / (1.0f + __expf(-gp));
                float rv = Xs[r][g];
                float av = Xs[r][Dx + g];
                float res = (gate * rv + (1.0f - gate) * av) * (float)mask[m0 + r];
                if (isbf) ((__hip_bfloat16*)outv)[(m0 + r) * Dx + g] = __float2bfloat16(res);
                else      ((float*)outv)[(m0 + r) * Dx + g] = res;
            }
        }
    }
}

extern "C" void kernel_launch(void* const* d_in, const int* in_sizes, int n_in,
                              void* d_out, int out_size, void* d_ws, size_t ws_size,
                              hipStream_t stream) {
    const void* X   = d_in[0];
    const int*  msk = (const int*)d_in[1];
    const void* Wfc = d_in[2];
    const void* bfc = d_in[3];
    const void* W1  = d_in[4];
    const void* W2  = d_in[5];
    const void* b1  = d_in[6];
    const void* Wf1 = d_in[7];
    const void* Wf2 = d_in[8];
    const void* bfv = d_in[9];
    float* ws = (float*)d_ws;
    void* outp = d_out;

    void* kargs[] = {
        (void*)&X, (void*)&msk, (void*)&Wfc, (void*)&bfc, (void*)&W1,
        (void*)&W2, (void*)&b1, (void*)&Wf1, (void*)&Wf2, (void*)&bfv,
        (void*)&ws, (void*)&outp
    };
    hipLaunchCooperativeKernel((void*)k_fused, dim3(256), dim3(320),
                               kargs, 0, stream);
}

// Round 6
// 206.520 us; speedup vs baseline: 1.6032x; 1.6032x over previous
//
#include <hip/hip_runtime.h>
#include <hip/hip_bf16.h>

#define Sx 256
#define Dx 300
#define Mx 1024
#define CC 5.0f

// workspace layout (float offsets)
#define OFF_REP    0
#define OFF_DEP    307200
#define OFF_HEAD   614400
#define OFF_ATTN   921600
#define OFF_WTFC   1228800   // [300k][300g]
#define OFF_WT12   1318800   // [300k][600g]  cols 0..299: W1 (dep), 300..599: W2 (head)
#define OFF_WTF12  1498800   // [600k][300g]  rows 0..299: Wf1, 300..599: Wf2
#define OFF_BIAS   1678800   // bfc@+0, b1@+304, bf@+608

__device__ __forceinline__ float bf2f(unsigned short u) {
    union { unsigned int i; float f; } v;
    v.i = ((unsigned int)u) << 16;
    return v.f;
}

__device__ __forceinline__ int detect_bf16(const void* w) {
    const unsigned short* u = (const unsigned short*)w;
    int ok = 1;
    #pragma unroll
    for (int t = 0; t < 64; ++t) {
        float v = bf2f(u[t]);
        ok &= (fabsf(v) < 1.0f) ? 1 : 0;
    }
    return ok;
}

__device__ __forceinline__ float ldf(const void* p, int idx, int isbf) {
    return isbf ? bf2f(((const unsigned short*)p)[idx]) : ((const float*)p)[idx];
}

// ---------------------------------------------------------------------------
// k_prep: transpose 5 weight matrices into fp32 WT layouts + biases.
// ---------------------------------------------------------------------------
__global__ __launch_bounds__(256) void k_prep(
        const void* __restrict__ Wfc, const void* __restrict__ W1,
        const void* __restrict__ W2,  const void* __restrict__ Wf1,
        const void* __restrict__ Wf2, const void* __restrict__ bfc,
        const void* __restrict__ b1,  const void* __restrict__ bfv,
        float* __restrict__ ws) {
    __shared__ float tile[32][33];
    __shared__ int s_isbf;
    if (threadIdx.x == 0) s_isbf = detect_bf16(Wfc);
    __syncthreads();
    const int isbf = s_isbf;
    const int bid = blockIdx.x;
    if (bid == 500) {
        for (int idx = threadIdx.x; idx < 912; idx += 256) {
            int wb = idx / 304, o = idx - wb * 304;
            const void* src = (wb == 0) ? bfc : (wb == 1 ? b1 : bfv);
            ws[OFF_BIAS + idx] = (o < Dx) ? ldf(src, o, isbf) : 0.0f;
        }
        return;
    }
    const int job = bid / 100, t = bid % 100;
    const int tg = t / 10, tk = t % 10;
    const void* src; float* dst; int stride, rowOff, colOff;
    switch (job) {
        case 0:  src = Wfc; dst = ws + OFF_WTFC;  stride = 300; rowOff = 0;   colOff = 0;   break;
        case 1:  src = W1;  dst = ws + OFF_WT12;  stride = 600; rowOff = 0;   colOff = 0;   break;
        case 2:  src = W2;  dst = ws + OFF_WT12;  stride = 600; rowOff = 0;   colOff = 300; break;
        case 3:  src = Wf1; dst = ws + OFF_WTF12; stride = 300; rowOff = 0;   colOff = 0;   break;
        default: src = Wf2; dst = ws + OFF_WTF12; stride = 300; rowOff = 300; colOff = 0;   break;
    }
    const int tx = threadIdx.x & 31, ty = threadIdx.x >> 5;
    #pragma unroll
    for (int r = 0; r < 4; ++r) {
        int g = tg * 32 + ty + r * 8, k = tk * 32 + tx;
        if (g < Dx && k < Dx) tile[ty + r * 8][tx] = ldf(src, g * Dx + k, isbf);
    }
    __syncthreads();
    #pragma unroll
    for (int r = 0; r < 4; ++r) {
        int k = tk * 32 + ty + r * 8, g = tg * 32 + tx;
        if (g < Dx && k < Dx) dst[(k + rowOff) * stride + colOff + g] = tile[tx][ty + r * 8];
    }
}

// ---------------------------------------------------------------------------
// k_repmap: rep = elu(X @ Wfc^T + bfc). 256 blocks x 640 thr.
// Waves 0-4: k in [0,152); waves 5-9: k in [152,300). X via wave-uniform
// (scalar) loads, W via coalesced vector loads. LDS only for k-reduction.
// ---------------------------------------------------------------------------
__global__ __launch_bounds__(640) void k_repmap(
        const void* __restrict__ Xv, const void* __restrict__ Wdet,
        const float* __restrict__ ws_ro, float* __restrict__ rep) {
    __shared__ float4 part[320];
    __shared__ int s_isbf;
    const int tid = threadIdx.x, m0 = blockIdx.x * 4;
    if (tid == 0) s_isbf = detect_bf16(Wdet);
    __syncthreads();
    const int isbf = s_isbf;
    const int kc = (tid >= 320);
    const int gl = kc ? tid - 320 : tid;
    const int g  = (gl < 300) ? gl : 299;     // clamped address, masked at store
    const int kg0 = kc ? 38 : 0, kg1 = kc ? 75 : 38;
    const float* WT = ws_ro + OFF_WTFC;
    float a0 = 0.f, a1 = 0.f, a2 = 0.f, a3 = 0.f;
    if (isbf) {
        const unsigned short* Xb = (const unsigned short*)Xv;
        const ushort4* xq0 = (const ushort4*)(Xb + (m0 + 0) * 300);
        const ushort4* xq1 = (const ushort4*)(Xb + (m0 + 1) * 300);
        const ushort4* xq2 = (const ushort4*)(Xb + (m0 + 2) * 300);
        const ushort4* xq3 = (const ushort4*)(Xb + (m0 + 3) * 300);
        #pragma unroll 4
        for (int kg = kg0; kg < kg1; ++kg) {
            const float* wp = WT + kg * 4 * 300 + g;
            float w0 = wp[0], w1 = wp[300], w2 = wp[600], w3 = wp[900];
            ushort4 u0 = xq0[kg], u1 = xq1[kg], u2 = xq2[kg], u3 = xq3[kg];
            a0 += bf2f(u0.x) * w0 + bf2f(u0.y) * w1 + bf2f(u0.z) * w2 + bf2f(u0.w) * w3;
            a1 += bf2f(u1.x) * w0 + bf2f(u1.y) * w1 + bf2f(u1.z) * w2 + bf2f(u1.w) * w3;
            a2 += bf2f(u2.x) * w0 + bf2f(u2.y) * w1 + bf2f(u2.z) * w2 + bf2f(u2.w) * w3;
            a3 += bf2f(u3.x) * w0 + bf2f(u3.y) * w1 + bf2f(u3.z) * w2 + bf2f(u3.w) * w3;
        }
    } else {
        const float* Xf = (const float*)Xv;
        const float4* xq0 = (const float4*)(Xf + (m0 + 0) * 300);
        const float4* xq1 = (const float4*)(Xf + (m0 + 1) * 300);
        const float4* xq2 = (const float4*)(Xf + (m0 + 2) * 300);
        const float4* xq3 = (const float4*)(Xf + (m0 + 3) * 300);
        #pragma unroll 4
        for (int kg = kg0; kg < kg1; ++kg) {
            const float* wp = WT + kg * 4 * 300 + g;
            float w0 = wp[0], w1 = wp[300], w2 = wp[600], w3 = wp[900];
            float4 x0 = xq0[kg], x1 = xq1[kg], x2 = xq2[kg], x3 = xq3[kg];
            a0 += x0.x * w0 + x0.y * w1 + x0.z * w2 + x0.w * w3;
            a1 += x1.x * w0 + x1.y * w1 + x1.z * w2 + x1.w * w3;
            a2 += x2.x * w0 + x2.y * w1 + x2.z * w2 + x2.w * w3;
            a3 += x3.x * w0 + x3.y * w1 + x3.z * w2 + x3.w * w3;
        }
    }
    if (kc) part[gl] = make_float4(a0, a1, a2, a3);
    __syncthreads();
    if (!kc && gl < 300) {
        float4 p = part[gl];
        float bb = ws_ro[OFF_BIAS + gl];
        float v0 = a0 + p.x + bb, v1 = a1 + p.y + bb, v2 = a2 + p.z + bb, v3 = a3 + p.w + bb;
        v0 = v0 > 0.f ? v0 : (__expf(v0) - 1.f);
        v1 = v1 > 0.f ? v1 : (__expf(v1) - 1.f);
        v2 = v2 > 0.f ? v2 : (__expf(v2) - 1.f);
        v3 = v3 > 0.f ? v3 : (__expf(v3) - 1.f);
        rep[(m0 + 0) * 300 + gl] = v0;
        rep[(m0 + 1) * 300 + gl] = v1;
        rep[(m0 + 2) * 300 + gl] = v2;
        rep[(m0 + 3) * 300 + gl] = v3;
    }
}

// ---------------------------------------------------------------------------
// k_dephead: 512 blocks x 640 thr. Even blocks: dep=rep@W1^T+b1; odd: head.
// Same scalar-X / vector-W / k-split-2 structure.
// ---------------------------------------------------------------------------
__global__ __launch_bounds__(640) void k_dephead(
        const float* __restrict__ ws_ro, float* __restrict__ ws) {
    __shared__ float4 part[320];
    const int tid = threadIdx.x;
    const int mt = blockIdx.x >> 1, half = blockIdx.x & 1;
    const int m0 = mt * 4;
    const int kc = (tid >= 320);
    const int gl = kc ? tid - 320 : tid;
    const int g  = (gl < 300) ? gl : 299;
    const int kg0 = kc ? 38 : 0, kg1 = kc ? 75 : 38;
    const float* WT = ws_ro + OFF_WT12 + half * 300;   // [300k][600]
    const float* rep = ws_ro + OFF_REP;
    const float4* xq0 = (const float4*)(rep + (m0 + 0) * 300);
    const float4* xq1 = (const float4*)(rep + (m0 + 1) * 300);
    const float4* xq2 = (const float4*)(rep + (m0 + 2) * 300);
    const float4* xq3 = (const float4*)(rep + (m0 + 3) * 300);
    float a0 = 0.f, a1 = 0.f, a2 = 0.f, a3 = 0.f;
    #pragma unroll 4
    for (int kg = kg0; kg < kg1; ++kg) {
        const float* wp = WT + kg * 4 * 600 + g;
        float w0 = wp[0], w1 = wp[600], w2 = wp[1200], w3 = wp[1800];
        float4 x0 = xq0[kg], x1 = xq1[kg], x2 = xq2[kg], x3 = xq3[kg];
        a0 += x0.x * w0 + x0.y * w1 + x0.z * w2 + x0.w * w3;
        a1 += x1.x * w0 + x1.y * w1 + x1.z * w2 + x1.w * w3;
        a2 += x2.x * w0 + x2.y * w1 + x2.z * w2 + x2.w * w3;
        a3 += x3.x * w0 + x3.y * w1 + x3.z * w2 + x3.w * w3;
    }
    if (kc) part[gl] = make_float4(a0, a1, a2, a3);
    __syncthreads();
    if (!kc && gl < 300) {
        float4 p = part[gl];
        float* dst = ws + (half ? OFF_HEAD : OFF_DEP);
        float bb = half ? 0.0f : ws_ro[OFF_BIAS + 304 + gl];
        dst[(m0 + 0) * 300 + gl] = a0 + p.x + bb;
        dst[(m0 + 1) * 300 + gl] = a1 + p.y + bb;
        dst[(m0 + 2) * 300 + gl] = a2 + p.z + bb;
        dst[(m0 + 3) * 300 + gl] = a3 + p.w + bb;
    }
}

// ---------------------------------------------------------------------------
// k_attn: single pass, branchless, fixed shift m=C (round-4 proven).
// grid 512, 320 thr; 2-i tiles long/short interleaved.
// ---------------------------------------------------------------------------
__global__ __launch_bounds__(320) void k_attn(
        const float* __restrict__ ws_ro, const int* __restrict__ mask,
        float* __restrict__ attn) {
    const float* dep  = ws_ro + OFF_DEP;
    const float* head = ws_ro + OFF_HEAD;
    const float* rep  = ws_ro + OFF_REP;
    __shared__ float mkf[256];
    const int blk = blockIdx.x;
    const int b = blk >> 7;
    const int tile = blk & 127;
    const int u = tile >> 1;
    const int i0 = (tile & 1) ? (254 - 2 * u) : (2 * u);
    const int tid = threadIdx.x;
    if (tid < 256) mkf[tid] = (float)mask[b * 256 + tid];
    __syncthreads();
    const int d = tid;
    if (d >= Dx) return;
    const int base = b * 256;

    const float hv0 = head[(base + i0) * Dx + d];
    const float hv1 = head[(base + i0 + 1) * Dx + d];
    const float pw0 = __expf(0.4f * hv0);
    const float pw1 = __expf(0.4f * hv1);

    float s0 = 0.f, r0 = 0.f, s1 = 0.f, r1 = 0.f;
    {
        const int j = i0 + 1;
        float dv = dep[(base + j) * Dx + d];
        float rv = rep[(base + j) * Dx + d];
        float mk = mkf[j];
        float ex = __expf(0.4f * dv);
        float u0 = fmaf(ex, pw0, 1.0f);
        float e0 = __expf(-10.0f * __builtin_amdgcn_rcpf(u0));
        float em0 = e0 * mk;
        s0 += em0; r0 = fmaf(em0, rv, r0);
    }
    const float* dp = dep + base * Dx + d;
    const float* rp = rep + base * Dx + d;
    #pragma unroll 4
    for (int j = i0 + 2; j < 256; ++j) {
        float dv = dp[j * Dx];
        float rv = rp[j * Dx];
        float mk = mkf[j];
        float ex = __expf(0.4f * dv);
        float u0 = fmaf(ex, pw0, 1.0f);
        float u1 = fmaf(ex, pw1, 1.0f);
        float e0 = __expf(-10.0f * __builtin_amdgcn_rcpf(u0));
        float e1 = __expf(-10.0f * __builtin_amdgcn_rcpf(u1));
        float em0 = e0 * mk;
        float em1 = e1 * mk;
        s0 += em0; r0 = fmaf(em0, rv, r0);
        s1 += em1; r1 = fmaf(em1, rv, r1);
    }
    const float den0 = s0 + (s0 == 0.f ? 1.f : 0.f) + 1e-20f;
    const float den1 = s1 + (s1 == 0.f ? 1.f : 0.f) + 1e-20f;
    attn[(base + i0) * Dx + d]     = r0 / den0;
    attn[(base + i0 + 1) * Dx + d] = r1 / den1;
}

// ---------------------------------------------------------------------------
// k_gate: 256 blocks x 640 thr. Waves 0-4: rep@Wf1^T; waves 5-9: attn@Wf2^T.
// Reduce, sigmoid, blend, mask, store.
// ---------------------------------------------------------------------------
__global__ __launch_bounds__(640) void k_gate(
        const float* __restrict__ ws_ro, const void* __restrict__ Wdet,
        const int* __restrict__ mask, void* __restrict__ outv) {
    __shared__ float4 part[320];
    __shared__ int s_isbf;
    const int tid = threadIdx.x, m0 = blockIdx.x * 4;
    if (tid == 0) s_isbf = detect_bf16(Wdet);
    __syncthreads();
    const int isbf = s_isbf;
    const int kc = (tid >= 320);
    const int gl = kc ? tid - 320 : tid;
    const int g  = (gl < 300) ? gl : 299;
    const float* WT = ws_ro + OFF_WTF12 + kc * 300 * 300;  // Wf1 rows / Wf2 rows
    const float* xbase = ws_ro + (kc ? OFF_ATTN : OFF_REP);
    const float4* xq0 = (const float4*)(xbase + (m0 + 0) * 300);
    const float4* xq1 = (const float4*)(xbase + (m0 + 1) * 300);
    const float4* xq2 = (const float4*)(xbase + (m0 + 2) * 300);
    const float4* xq3 = (const float4*)(xbase + (m0 + 3) * 300);
    float a0 = 0.f, a1 = 0.f, a2 = 0.f, a3 = 0.f;
    #pragma unroll 4
    for (int kg = 0; kg < 75; ++kg) {
        const float* wp = WT + kg * 4 * 300 + g;
        float w0 = wp[0], w1 = wp[300], w2 = wp[600], w3 = wp[900];
        float4 x0 = xq0[kg], x1 = xq1[kg], x2 = xq2[kg], x3 = xq3[kg];
        a0 += x0.x * w0 + x0.y * w1 + x0.z * w2 + x0.w * w3;
        a1 += x1.x * w0 + x1.y * w1 + x1.z * w2 + x1.w * w3;
        a2 += x2.x * w0 + x2.y * w1 + x2.z * w2 + x2.w * w3;
        a3 += x3.x * w0 + x3.y * w1 + x3.z * w2 + x3.w * w3;
    }
    if (kc) part[gl] = make_float4(a0, a1, a2, a3);
    __syncthreads();
    if (!kc && gl < 300) {
        float4 p = part[gl];
        float bb = ws_ro[OFF_BIAS + 608 + gl];
        const float* rep  = ws_ro + OFF_REP;
        const float* attn = ws_ro + OFF_ATTN;
        #pragma unroll
        for (int r = 0; r < 4; ++r) {
            float acc = (r == 0 ? a0 + p.x : r == 1 ? a1 + p.y : r == 2 ? a2 + p.z : a3 + p.w);
            float gp = acc + bb;
            float gate = 1.0f / (1.0f + __expf(-gp));
            float rv = rep[(m0 + r) * 300 + gl];
            float av = attn[(m0 + r) * 300 + gl];
            float res = (gate * rv + (1.0f - gate) * av) * (float)mask[m0 + r];
            if (isbf) ((__hip_bfloat16*)outv)[(m0 + r) * 300 + gl] = __float2bfloat16(res);
            else      ((float*)outv)[(m0 + r) * 300 + gl] = res;
        }
    }
}

extern "C" void kernel_launch(void* const* d_in, const int* in_sizes, int n_in,
                              void* d_out, int out_size, void* d_ws, size_t ws_size,
                              hipStream_t stream) {
    const void* X   = d_in[0];
    const int*  msk = (const int*)d_in[1];
    const void* Wfc = d_in[2];
    const void* bfc = d_in[3];
    const void* W1  = d_in[4];
    const void* W2  = d_in[5];
    const void* b1  = d_in[6];
    const void* Wf1 = d_in[7];
    const void* Wf2 = d_in[8];
    const void* bfv = d_in[9];
    float* ws = (float*)d_ws;

    hipLaunchKernelGGL(k_prep,    dim3(501), dim3(256), 0, stream,
                       Wfc, W1, W2, Wf1, Wf2, bfc, b1, bfv, ws);
    hipLaunchKernelGGL(k_repmap,  dim3(256), dim3(640), 0, stream,
                       X, Wfc, ws, ws + OFF_REP);
    hipLaunchKernelGGL(k_dephead, dim3(512), dim3(640), 0, stream, ws, ws);
    hipLaunchKernelGGL(k_attn,    dim3(512), dim3(320), 0, stream,
                       ws, msk, ws + OFF_ATTN);
    hipLaunchKernelGGL(k_gate,    dim3(256), dim3(640), 0, stream,
                       ws, Wf1, msk, d_out);
}